// Round 3
// baseline (3967.062 us; speedup 1.0000x reference)
//
#include <hip/hip_runtime.h>
#include <hip/hip_bf16.h>
#include <math.h>

#define BB 4
#define NN 4096
#define CC 256
#define KK 16
#define AA 256
#define NPTS (BB*NN)            // 16384
#define BNKTOT (NPTS*KK)        // 262144
#define EPSF 1e-5f
#define MINVF (1.0f/262144.0f)

// stats / consts float offsets
#define ST_BND_SUM 0
#define ST_BND_SQ  8
#define ST_G1_SUM  16
#define ST_G1_SQ   272
#define ST_G2_SUM  528
#define ST_G2_SQ   784
#define CO_BND_S   0
#define CO_BND_B   4
#define CO_G1_S    16
#define CO_G1_B    272
#define CO_G2_S    528
#define CO_G2_B    784

__device__ inline float waveReduceAdd(float v) {
    #pragma unroll
    for (int o = 32; o > 0; o >>= 1) v += __shfl_down(v, o);
    return v;
}

// ---------------- K1: q/k/v projections ----------------
// grid (NPTS/64, 3), block 256. blockIdx.y selects which weight.
__global__ __launch_bounds__(256) void qkv_kernel(
    const float* __restrict__ feat,
    const float* __restrict__ wq, const float* __restrict__ bq,
    const float* __restrict__ wk, const float* __restrict__ bk,
    const float* __restrict__ wv, const float* __restrict__ bv,
    float* __restrict__ oq, float* __restrict__ ok, float* __restrict__ ov)
{
    const float* W; const float* bias; float* out;
    if (blockIdx.y == 0)      { W = wq; bias = bq; out = oq; }
    else if (blockIdx.y == 1) { W = wk; bias = bk; out = ok; }
    else                      { W = wv; bias = bv; out = ov; }

    const int p0 = blockIdx.x * 64;
    const int t  = threadIdx.x;          // output channel c
    __shared__ __align__(16) float fs[64][65];

    float acc[64];
    #pragma unroll
    for (int p = 0; p < 64; ++p) acc[p] = 0.f;

    for (int it = 0; it < 4; ++it) {
        // stage 64 pts x 64 inputs
        const int tp = t >> 2;
        #pragma unroll
        for (int q = 0; q < 4; ++q) {
            const int ch = (t & 3) + q * 4;             // 0..15 float4 chunks
            float4 v = *(const float4*)&feat[(size_t)(p0 + tp) * CC + it * 64 + ch * 4];
            fs[tp][ch*4+0] = v.x; fs[tp][ch*4+1] = v.y; fs[tp][ch*4+2] = v.z; fs[tp][ch*4+3] = v.w;
        }
        __syncthreads();
        #pragma unroll 4
        for (int i = 0; i < 64; ++i) {
            const float w = W[(size_t)(it * 64 + i) * CC + t];
            #pragma unroll
            for (int p = 0; p < 64; ++p) acc[p] = fmaf(fs[p][i], w, acc[p]);
        }
        __syncthreads();
    }
    const float bv_ = bias[t];
    #pragma unroll
    for (int p = 0; p < 64; ++p) out[(size_t)(p0 + p) * CC + t] = acc[p] + bv_;
}

// ---------------- K2: KNN top-16 ----------------
// grid 64 blocks x 256 threads; one query per thread.
__global__ __launch_bounds__(256) void knn_kernel(
    const float* __restrict__ xyz, int* __restrict__ idxout)
{
    const int b = blockIdx.x >> 4;
    const int n = ((blockIdx.x & 15) << 8) + threadIdx.x;
    const float* xb = xyz + (size_t)b * NN * 3;

    const float qx = xb[n*3+0], qy = xb[n*3+1], qz = xb[n*3+2];
    const float sqn = qx*qx + qy*qy + qz*qz;

    __shared__ float4 tile[512];

    float bd[16]; int bi[16];
    #pragma unroll
    for (int s = 0; s < 16; ++s) { bd[s] = 1e30f; bi[s] = 0; }

    for (int t0 = 0; t0 < NN; t0 += 512) {
        #pragma unroll
        for (int q = 0; q < 2; ++q) {
            const int j = threadIdx.x + q * 256;
            const float x = xb[(t0 + j)*3 + 0];
            const float y = xb[(t0 + j)*3 + 1];
            const float z = xb[(t0 + j)*3 + 2];
            tile[j] = make_float4(x, y, z, x*x + y*y + z*z);
        }
        __syncthreads();
        #pragma unroll 2
        for (int j = 0; j < 512; ++j) {
            const float4 p = tile[j];
            const float d = sqn + p.w - 2.0f * (qx*p.x + qy*p.y + qz*p.z);
            if (d < bd[15]) {
                const int m = t0 + j;
                bool placed = false;
                #pragma unroll
                for (int s = 15; s > 0; --s) {
                    if (!placed) {
                        if (bd[s-1] > d) { bd[s] = bd[s-1]; bi[s] = bi[s-1]; }
                        else             { bd[s] = d; bi[s] = m; placed = true; }
                    }
                }
                if (!placed) { bd[0] = d; bi[0] = m; }
            }
        }
        __syncthreads();
    }
    #pragma unroll
    for (int s = 0; s < 16; ++s) idxout[((size_t)b * NN + n) * KK + s] = bi[s];
}

// ---------------- K3: t = rel@d1_w + d1_b, bn_d stats ----------------
__global__ __launch_bounds__(256) void fc_delta_kernel(
    const float* __restrict__ xyz, const int* __restrict__ idx,
    const float* __restrict__ d1w, const float* __restrict__ d1b,
    float* __restrict__ t3, float* __restrict__ stats)
{
    const int g = blockIdx.x * 256 + threadIdx.x;   // 0..262143
    const int b = g >> 16;
    const int rem = g & 65535;
    const int n = rem >> 4;
    const int mi = idx[g];
    const float* xb = xyz + (size_t)b * NN * 3;
    const float rx = xb[n*3+0] - xb[mi*3+0];
    const float ry = xb[n*3+1] - xb[mi*3+1];
    const float rz = xb[n*3+2] - xb[mi*3+2];
    float tv[3];
    #pragma unroll
    for (int j = 0; j < 3; ++j) {
        tv[j] = fmaf(rx, d1w[0*3+j], fmaf(ry, d1w[1*3+j], fmaf(rz, d1w[2*3+j], d1b[j])));
        t3[(size_t)g*3 + j] = tv[j];
    }
    const int lane = threadIdx.x & 63;
    #pragma unroll
    for (int j = 0; j < 3; ++j) {
        float s  = waveReduceAdd(tv[j]);
        float sq = waveReduceAdd(tv[j]*tv[j]);
        if (lane == 0) {
            atomicAdd(&stats[ST_BND_SUM + j], s);
            atomicAdd(&stats[ST_BND_SQ + j], sq);
        }
    }
}

// ---------------- finalize bn_d ----------------
__global__ void finalize_bnd(const float* __restrict__ stats,
                             const float* __restrict__ g, const float* __restrict__ b,
                             float* __restrict__ consts)
{
    const int t = threadIdx.x;
    if (t < 3) {
        const float m = stats[ST_BND_SUM + t] * MINVF;
        const float v = stats[ST_BND_SQ + t] * MINVF - m * m;
        const float s = g[t] / sqrtf(v + EPSF);
        consts[CO_BND_S + t] = s;
        consts[CO_BND_B + t] = b[t] - m * s;
    }
}

// ---------------- K5: g_bn1 stats ----------------
// grid 1024 (b, 16-point chunk), block 256 (thread = channel c)
__global__ __launch_bounds__(256) void bn1_stats_kernel(
    const float* __restrict__ qproj, const float* __restrict__ kproj,
    const float* __restrict__ t3, const int* __restrict__ idx,
    const float* __restrict__ consts,
    const float* __restrict__ d2w, const float* __restrict__ d2b,
    float* __restrict__ stats)
{
    const int b   = blockIdx.x >> 8;
    const int pt0 = (blockIdx.x & 255) * 16;
    const int t = threadIdx.x;

    __shared__ float a3[768];
    __shared__ int idxs[256];

    const float bs[3]  = {consts[CO_BND_S+0], consts[CO_BND_S+1], consts[CO_BND_S+2]};
    const float bsh[3] = {consts[CO_BND_B+0], consts[CO_BND_B+1], consts[CO_BND_B+2]};
    const float* t3b = t3 + (size_t)(b * NN + pt0) * KK * 3;
    #pragma unroll
    for (int q = 0; q < 3; ++q) {
        const int f = t + q * 256;
        const int j = f % 3;
        a3[f] = fmaxf(fmaf(t3b[f], bs[j], bsh[j]), 0.f);
    }
    idxs[t] = idx[(size_t)(b * NN + pt0) * KK + t];
    __syncthreads();

    const int c = t;
    const float d20 = d2w[c], d21 = d2w[CC + c], d22 = d2w[2*CC + c], d2bc = d2b[c];
    float s = 0.f, sq = 0.f;
    for (int p = 0; p < 16; ++p) {
        const float qv = qproj[(size_t)(b * NN + pt0 + p) * CC + c];
        #pragma unroll
        for (int k = 0; k < 16; ++k) {
            const int mi = idxs[p*16 + k];
            const float kv = kproj[((size_t)b * NN + mi) * CC + c];
            const int f = (p*16 + k) * 3;
            const float pe = fmaf(a3[f], d20, fmaf(a3[f+1], d21, fmaf(a3[f+2], d22, d2bc)));
            const float h = qv - kv + pe;
            s += h; sq = fmaf(h, h, sq);
        }
    }
    atomicAdd(&stats[ST_G1_SUM + c], s);
    atomicAdd(&stats[ST_G1_SQ + c], sq);
}

// ---------------- finalize g_bn (shared by bn1 / bn2) ----------------
__global__ void finalize_g(const float* __restrict__ ssum, const float* __restrict__ ssq,
                           const float* __restrict__ g, const float* __restrict__ b,
                           float* __restrict__ os, float* __restrict__ ob)
{
    const int c = threadIdx.x;
    const float m = ssum[c] * MINVF;
    const float v = ssq[c] * MINVF - m * m;
    const float s = g[c] / sqrtf(v + EPSF);
    os[c] = s;
    ob[c] = b[c] - m * s;
}

// ---------------- K7: stage3 — h2 = relu(bn1(h)) @ g1_w + g1_b; bn2 stats ----------------
template<bool STORE>
__global__ __launch_bounds__(256) void stage3_kernel(
    const float* __restrict__ qproj, const float* __restrict__ kproj,
    const float* __restrict__ t3, const int* __restrict__ idx,
    const float* __restrict__ consts, float* __restrict__ stats,
    const float* __restrict__ d2w, const float* __restrict__ d2b,
    const float* __restrict__ g1w, const float* __restrict__ g1b,
    __hip_bfloat16* __restrict__ h2)
{
    const size_t pt = blockIdx.x;            // b*N + n
    const int b = (int)(pt >> 12);
    const int t = threadIdx.x;

    __shared__ float a3[48];
    __shared__ int idxs[16];
    __shared__ __align__(16) float hr[16][256];

    if (t < 48) {
        const int j = t % 3;
        a3[t] = fmaxf(fmaf(t3[pt*48 + t], consts[CO_BND_S + j], consts[CO_BND_B + j]), 0.f);
    }
    if (t < 16) idxs[t] = idx[pt*16 + t];
    __syncthreads();

    {   // phase 1: h -> bn1 -> relu into LDS
        const int c = t;
        const float d20 = d2w[c], d21 = d2w[CC + c], d22 = d2w[2*CC + c], d2bc = d2b[c];
        const float g1s = consts[CO_G1_S + c], g1sh = consts[CO_G1_B + c];
        const float qv = qproj[pt * CC + c];
        #pragma unroll
        for (int k = 0; k < 16; ++k) {
            const int mi = idxs[k];
            const float kv = kproj[((size_t)b * NN + mi) * CC + c];
            const float pe = fmaf(a3[k*3], d20, fmaf(a3[k*3+1], d21, fmaf(a3[k*3+2], d22, d2bc)));
            const float h = qv - kv + pe;
            hr[k][c] = fmaxf(fmaf(h, g1s, g1sh), 0.f);
        }
    }
    __syncthreads();

    // phase 2: GEMM1 (16x256 @ 256x256), thread = output channel a
    float acc[16];
    const float gb = g1b[t];
    #pragma unroll
    for (int k = 0; k < 16; ++k) acc[k] = gb;
    #pragma unroll 4
    for (int c4 = 0; c4 < 64; ++c4) {
        const float* wp = g1w + (size_t)(c4*4) * AA + t;
        const float w0 = wp[0], w1 = wp[AA], w2 = wp[2*AA], w3 = wp[3*AA];
        #pragma unroll
        for (int k = 0; k < 16; ++k) {
            const float4 hv = *(const float4*)&hr[k][c4*4];
            acc[k] = fmaf(hv.x, w0, fmaf(hv.y, w1, fmaf(hv.z, w2, fmaf(hv.w, w3, acc[k]))));
        }
    }

    float s = 0.f, sq = 0.f;
    #pragma unroll
    for (int k = 0; k < 16; ++k) { s += acc[k]; sq = fmaf(acc[k], acc[k], sq); }
    atomicAdd(&stats[ST_G2_SUM + t], s);
    atomicAdd(&stats[ST_G2_SQ + t], sq);

    if (STORE) {
        #pragma unroll
        for (int k = 0; k < 16; ++k)
            h2[(pt*16 + k) * AA + t] = __float2bfloat16(acc[k]);
    }
}

// ---------------- K9: stage4 — GEMM2, softmax, combine ----------------
template<bool LOAD>
__global__ __launch_bounds__(256) void stage4_kernel(
    const float* __restrict__ qproj, const float* __restrict__ kproj,
    const float* __restrict__ vproj,
    const float* __restrict__ t3, const int* __restrict__ idx,
    const float* __restrict__ consts,
    const float* __restrict__ d2w, const float* __restrict__ d2b,
    const float* __restrict__ g1w, const float* __restrict__ g1b,
    const float* __restrict__ g2w, const float* __restrict__ g2b,
    const __hip_bfloat16* __restrict__ h2, float* __restrict__ out)
{
    const size_t pt = blockIdx.x;
    const int b = (int)(pt >> 12);
    const int t = threadIdx.x;

    __shared__ float a3[48];
    __shared__ int idxs[16];
    __shared__ __align__(16) float r2[16][256];

    if (t < 48) {
        const int j = t % 3;
        a3[t] = fmaxf(fmaf(t3[pt*48 + t], consts[CO_BND_S + j], consts[CO_BND_B + j]), 0.f);
    }
    if (t < 16) idxs[t] = idx[pt*16 + t];
    __syncthreads();

    const float g2s = consts[CO_G2_S + t], g2sh = consts[CO_G2_B + t];

    if constexpr (LOAD) {
        #pragma unroll
        for (int k = 0; k < 16; ++k) {
            const float v = __bfloat162float(h2[(pt*16 + k) * AA + t]);
            r2[k][t] = fmaxf(fmaf(v, g2s, g2sh), 0.f);
        }
        __syncthreads();
    } else {
        __shared__ __align__(16) float hr[16][256];
        {
            const int c = t;
            const float d20 = d2w[c], d21 = d2w[CC + c], d22 = d2w[2*CC + c], d2bc = d2b[c];
            const float g1s = consts[CO_G1_S + c], g1sh = consts[CO_G1_B + c];
            const float qv = qproj[pt * CC + c];
            #pragma unroll
            for (int k = 0; k < 16; ++k) {
                const int mi = idxs[k];
                const float kv = kproj[((size_t)b * NN + mi) * CC + c];
                const float pe = fmaf(a3[k*3], d20, fmaf(a3[k*3+1], d21, fmaf(a3[k*3+2], d22, d2bc)));
                const float h = qv - kv + pe;
                hr[k][c] = fmaxf(fmaf(h, g1s, g1sh), 0.f);
            }
        }
        __syncthreads();
        float acc[16];
        const float gb = g1b[t];
        #pragma unroll
        for (int k = 0; k < 16; ++k) acc[k] = gb;
        #pragma unroll 4
        for (int c4 = 0; c4 < 64; ++c4) {
            const float* wp = g1w + (size_t)(c4*4) * AA + t;
            const float w0 = wp[0], w1 = wp[AA], w2 = wp[2*AA], w3 = wp[3*AA];
            #pragma unroll
            for (int k = 0; k < 16; ++k) {
                const float4 hv = *(const float4*)&hr[k][c4*4];
                acc[k] = fmaf(hv.x, w0, fmaf(hv.y, w1, fmaf(hv.z, w2, fmaf(hv.w, w3, acc[k]))));
            }
        }
        __syncthreads();   // hr no longer needed
        #pragma unroll
        for (int k = 0; k < 16; ++k) r2[k][t] = fmaxf(fmaf(acc[k], g2s, g2sh), 0.f);
        __syncthreads();
    }

    // GEMM2: logits[k][a], thread = a
    float lg[16];
    const float gb2 = g2b[t];
    #pragma unroll
    for (int k = 0; k < 16; ++k) lg[k] = gb2;
    #pragma unroll 4
    for (int c4 = 0; c4 < 64; ++c4) {
        const float* wp = g2w + (size_t)(c4*4) * AA + t;
        const float w0 = wp[0], w1 = wp[AA], w2 = wp[2*AA], w3 = wp[3*AA];
        #pragma unroll
        for (int k = 0; k < 16; ++k) {
            const float4 hv = *(const float4*)&r2[k][c4*4];
            lg[k] = fmaf(hv.x, w0, fmaf(hv.y, w1, fmaf(hv.z, w2, fmaf(hv.w, w3, lg[k]))));
        }
    }

    // softmax over k (all in registers)
    float mx = lg[0];
    #pragma unroll
    for (int k = 1; k < 16; ++k) mx = fmaxf(mx, lg[k]);
    float sum = 0.f;
    #pragma unroll
    for (int k = 0; k < 16; ++k) { lg[k] = expf(lg[k] - mx); sum += lg[k]; }
    const float inv = 1.0f / sum;

    // combine: out = sum_k (v + pos_enc) * attn
    const float d20 = d2w[t], d21 = d2w[CC + t], d22 = d2w[2*CC + t], d2bc = d2b[t];
    float o = 0.f;
    #pragma unroll
    for (int k = 0; k < 16; ++k) {
        const int mi = idxs[k];
        const float vv = vproj[((size_t)b * NN + mi) * CC + t];
        const float pe = fmaf(a3[k*3], d20, fmaf(a3[k*3+1], d21, fmaf(a3[k*3+2], d22, d2bc)));
        o = fmaf(vv + pe, lg[k] * inv, o);
    }
    out[pt * CC + t] = o;
}

// ---------------- host ----------------
extern "C" void kernel_launch(void* const* d_in, const int* in_sizes, int n_in,
                              void* d_out, int out_size, void* d_ws, size_t ws_size,
                              hipStream_t stream)
{
    const float* xyz   = (const float*)d_in[0];
    const float* feat  = (const float*)d_in[1];
    const float* wq    = (const float*)d_in[2];
    const float* bq    = (const float*)d_in[3];
    const float* wk    = (const float*)d_in[4];
    const float* bk    = (const float*)d_in[5];
    const float* wv    = (const float*)d_in[6];
    const float* bv    = (const float*)d_in[7];
    const float* d1w   = (const float*)d_in[8];
    const float* d1b   = (const float*)d_in[9];
    const float* bndg  = (const float*)d_in[10];
    const float* bndb  = (const float*)d_in[11];
    const float* d2w   = (const float*)d_in[12];
    const float* d2b   = (const float*)d_in[13];
    const float* g1g   = (const float*)d_in[14];
    const float* g1bb  = (const float*)d_in[15];
    const float* g1w   = (const float*)d_in[16];
    const float* g1b   = (const float*)d_in[17];
    const float* g2g   = (const float*)d_in[18];
    const float* g2bb  = (const float*)d_in[19];
    const float* g2w   = (const float*)d_in[20];
    const float* g2b   = (const float*)d_in[21];
    float* out = (float*)d_out;

    // workspace layout
    float* qproj = (float*)d_ws;
    float* kproj = qproj + (size_t)NPTS * CC;
    float* vproj = kproj + (size_t)NPTS * CC;
    float* t3    = vproj + (size_t)NPTS * CC;
    float* stats = t3 + (size_t)BNKTOT * 3;
    float* consts = stats + 2048;
    int*   idxb  = (int*)(consts + 2048);
    __hip_bfloat16* h2 = (__hip_bfloat16*)(idxb + BNKTOT);
    const size_t need_store = (size_t)((char*)h2 - (char*)d_ws) + (size_t)BNKTOT * AA * 2;
    const bool store = ws_size >= need_store;

    hipMemsetAsync(stats, 0, 2048 * sizeof(float), stream);

    dim3 gq(NPTS / 64, 3);
    qkv_kernel<<<gq, 256, 0, stream>>>(feat, wq, bq, wk, bk, wv, bv, qproj, kproj, vproj);

    knn_kernel<<<64, 256, 0, stream>>>(xyz, idxb);

    fc_delta_kernel<<<BNKTOT / 256, 256, 0, stream>>>(xyz, idxb, d1w, d1b, t3, stats);

    finalize_bnd<<<1, 64, 0, stream>>>(stats, bndg, bndb, consts);

    bn1_stats_kernel<<<1024, 256, 0, stream>>>(qproj, kproj, t3, idxb, consts, d2w, d2b, stats);

    finalize_g<<<1, 256, 0, stream>>>(stats + ST_G1_SUM, stats + ST_G1_SQ, g1g, g1bb,
                                      consts + CO_G1_S, consts + CO_G1_B);

    if (store)
        stage3_kernel<true><<<NPTS, 256, 0, stream>>>(qproj, kproj, t3, idxb, consts, stats,
                                                      d2w, d2b, g1w, g1b, h2);
    else
        stage3_kernel<false><<<NPTS, 256, 0, stream>>>(qproj, kproj, t3, idxb, consts, stats,
                                                       d2w, d2b, g1w, g1b, h2);

    finalize_g<<<1, 256, 0, stream>>>(stats + ST_G2_SUM, stats + ST_G2_SQ, g2g, g2bb,
                                      consts + CO_G2_S, consts + CO_G2_B);

    if (store)
        stage4_kernel<true><<<NPTS, 256, 0, stream>>>(qproj, kproj, vproj, t3, idxb, consts,
                                                      d2w, d2b, g1w, g1b, g2w, g2b, h2, out);
    else
        stage4_kernel<false><<<NPTS, 256, 0, stream>>>(qproj, kproj, vproj, t3, idxb, consts,
                                                       d2w, d2b, g1w, g1b, g2w, g2b, h2, out);
}

// Round 4
// 2615.357 us; speedup vs baseline: 1.5168x; 1.5168x over previous
//
#include <hip/hip_runtime.h>
#include <hip/hip_bf16.h>
#include <math.h>

#define BB 4
#define NN 4096
#define CC 256
#define KK 16
#define AA 256
#define NPTS (BB*NN)            // 16384
#define BNKTOT (NPTS*KK)        // 262144
#define EPSF 1e-5f
#define MINVF (1.0f/262144.0f)

// stats / consts float offsets
#define ST_BND_SUM 0
#define ST_BND_SQ  8
#define ST_G1_SUM  16
#define ST_G1_SQ   272
#define ST_G2_SUM  528
#define ST_G2_SQ   784
#define CO_BND_S   0
#define CO_BND_B   4
#define CO_G1_S    16
#define CO_G1_B    272
#define CO_G2_S    528
#define CO_G2_B    784

__device__ inline float waveReduceAdd(float v) {
    #pragma unroll
    for (int o = 32; o > 0; o >>= 1) v += __shfl_down(v, o);
    return v;
}

// ---------------- K1: q/k/v projections ----------------
// grid (NPTS/64, 3), block 256. blockIdx.y selects which weight.
__global__ __launch_bounds__(256) void qkv_kernel(
    const float* __restrict__ feat,
    const float* __restrict__ wq, const float* __restrict__ bq,
    const float* __restrict__ wk, const float* __restrict__ bk,
    const float* __restrict__ wv, const float* __restrict__ bv,
    float* __restrict__ oq, float* __restrict__ ok, float* __restrict__ ov)
{
    const float* W; const float* bias; float* out;
    if (blockIdx.y == 0)      { W = wq; bias = bq; out = oq; }
    else if (blockIdx.y == 1) { W = wk; bias = bk; out = ok; }
    else                      { W = wv; bias = bv; out = ov; }

    const int p0 = blockIdx.x * 64;
    const int t  = threadIdx.x;          // output channel c
    __shared__ __align__(16) float fs[64][65];

    float acc[64];
    #pragma unroll
    for (int p = 0; p < 64; ++p) acc[p] = 0.f;

    for (int it = 0; it < 4; ++it) {
        // stage 64 pts x 64 inputs
        const int tp = t >> 2;
        #pragma unroll
        for (int q = 0; q < 4; ++q) {
            const int ch = (t & 3) + q * 4;             // 0..15 float4 chunks
            float4 v = *(const float4*)&feat[(size_t)(p0 + tp) * CC + it * 64 + ch * 4];
            fs[tp][ch*4+0] = v.x; fs[tp][ch*4+1] = v.y; fs[tp][ch*4+2] = v.z; fs[tp][ch*4+3] = v.w;
        }
        __syncthreads();
        #pragma unroll 4
        for (int i = 0; i < 64; ++i) {
            const float w = W[(size_t)(it * 64 + i) * CC + t];
            #pragma unroll
            for (int p = 0; p < 64; ++p) acc[p] = fmaf(fs[p][i], w, acc[p]);
        }
        __syncthreads();
    }
    const float bv_ = bias[t];
    #pragma unroll
    for (int p = 0; p < 64; ++p) out[(size_t)(p0 + p) * CC + t] = acc[p] + bv_;
}

// ---------------- K2: KNN top-16 (query x candidate-chunk parallel) ----------------
// grid 512 blocks x 256 threads. Each block: 32 queries x 8 stride-8 chunks.
// Thread (q = t>>3, c = t&7) keeps a register top-16 over candidates j with
// j%8==c (512 of them), then 8 sorted partial lists per query are merged
// exactly (tie-break: smaller index) by threads 0..31.
// __launch_bounds__(256,2): VGPR cap 256 so bd[16]/bi[16] stay in registers
// (baseline's (256) default capped VGPR=32 -> scratch-spilled queue, 1587us).
__global__ __launch_bounds__(256, 2) void knn_kernel(
    const float* __restrict__ xyz, int* __restrict__ idxout)
{
    const int t = threadIdx.x;
    const int q = t >> 3;                      // 0..31 query slot
    const int c = t & 7;                       // 0..7 chunk
    const int b = blockIdx.x >> 7;             // 128 blocks per batch
    const int n = ((blockIdx.x & 127) << 5) + q;
    const float* xb = xyz + (size_t)b * NN * 3;

    const float qx = xb[n*3+0], qy = xb[n*3+1], qz = xb[n*3+2];
    const float sqn = qx*qx + qy*qy + qz*qz;

    __shared__ float4 tile[512];
    __shared__ float pl_d[8][17][33];          // [chunk][slot(pad17)][query(pad33)]
    __shared__ int   pl_i[8][17][33];

    float bd[16]; int bi[16];
    #pragma unroll
    for (int s = 0; s < 16; ++s) { bd[s] = 1e30f; bi[s] = 0; }

    for (int t0 = 0; t0 < NN; t0 += 512) {
        #pragma unroll
        for (int r = 0; r < 2; ++r) {
            const int j = t + r * 256;
            const float x = xb[(t0 + j)*3 + 0];
            const float y = xb[(t0 + j)*3 + 1];
            const float z = xb[(t0 + j)*3 + 2];
            tile[j] = make_float4(x, y, z, x*x + y*y + z*z);
        }
        __syncthreads();
        for (int j0 = 0; j0 < 512; j0 += 8) {
            const int j = j0 + c;
            const float4 p = tile[j];
            const float d = sqn + p.w - 2.0f * (qx*p.x + qy*p.y + qz*p.z);
            if (d < bd[15]) {
                const int m = t0 + j;
                bool placed = false;
                #pragma unroll
                for (int s = 15; s > 0; --s) {
                    if (!placed) {
                        if (bd[s-1] > d) { bd[s] = bd[s-1]; bi[s] = bi[s-1]; }
                        else             { bd[s] = d; bi[s] = m; placed = true; }
                    }
                }
                if (!placed) { bd[0] = d; bi[0] = m; }
            }
        }
        __syncthreads();
    }

    // dump partial sorted lists to LDS
    #pragma unroll
    for (int s = 0; s < 16; ++s) { pl_d[c][s][q] = bd[s]; pl_i[c][s][q] = bi[s]; }
    __syncthreads();

    // exact 8-way merge, one query per thread (threads 0..31)
    if (t < 32) {
        const int qq = t;
        float hd[8]; int hi[8]; int p[8];
        #pragma unroll
        for (int cc = 0; cc < 8; ++cc) {
            hd[cc] = pl_d[cc][0][qq]; hi[cc] = pl_i[cc][0][qq]; p[cc] = 1;
        }
        const int nq = ((blockIdx.x & 127) << 5) + qq;
        int* op = idxout + ((size_t)b * NN + nq) * KK;
        #pragma unroll
        for (int s = 0; s < 16; ++s) {
            float bdv = hd[0]; int biv = hi[0]; int bc = 0;
            #pragma unroll
            for (int cc = 1; cc < 8; ++cc) {
                const bool better = (hd[cc] < bdv) || (hd[cc] == bdv && hi[cc] < biv);
                if (better) { bdv = hd[cc]; biv = hi[cc]; bc = cc; }
            }
            op[s] = biv;
            #pragma unroll
            for (int cc = 0; cc < 8; ++cc) {
                if (bc == cc) {
                    const int pp = p[cc];
                    const bool ok = pp < 16;
                    hd[cc] = ok ? pl_d[cc][pp][qq] : 1e38f;   // [16] read stays in pad
                    hi[cc] = ok ? pl_i[cc][pp][qq] : 0;
                    p[cc] = pp + 1;
                }
            }
        }
    }
}

// ---------------- K3: t = rel@d1_w + d1_b, bn_d stats ----------------
__global__ __launch_bounds__(256) void fc_delta_kernel(
    const float* __restrict__ xyz, const int* __restrict__ idx,
    const float* __restrict__ d1w, const float* __restrict__ d1b,
    float* __restrict__ t3, float* __restrict__ stats)
{
    const int g = blockIdx.x * 256 + threadIdx.x;   // 0..262143
    const int b = g >> 16;
    const int rem = g & 65535;
    const int n = rem >> 4;
    const int mi = idx[g];
    const float* xb = xyz + (size_t)b * NN * 3;
    const float rx = xb[n*3+0] - xb[mi*3+0];
    const float ry = xb[n*3+1] - xb[mi*3+1];
    const float rz = xb[n*3+2] - xb[mi*3+2];
    float tv[3];
    #pragma unroll
    for (int j = 0; j < 3; ++j) {
        tv[j] = fmaf(rx, d1w[0*3+j], fmaf(ry, d1w[1*3+j], fmaf(rz, d1w[2*3+j], d1b[j])));
        t3[(size_t)g*3 + j] = tv[j];
    }
    const int lane = threadIdx.x & 63;
    #pragma unroll
    for (int j = 0; j < 3; ++j) {
        float s  = waveReduceAdd(tv[j]);
        float sq = waveReduceAdd(tv[j]*tv[j]);
        if (lane == 0) {
            atomicAdd(&stats[ST_BND_SUM + j], s);
            atomicAdd(&stats[ST_BND_SQ + j], sq);
        }
    }
}

// ---------------- finalize bn_d ----------------
__global__ void finalize_bnd(const float* __restrict__ stats,
                             const float* __restrict__ g, const float* __restrict__ b,
                             float* __restrict__ consts)
{
    const int t = threadIdx.x;
    if (t < 3) {
        const float m = stats[ST_BND_SUM + t] * MINVF;
        const float v = stats[ST_BND_SQ + t] * MINVF - m * m;
        const float s = g[t] / sqrtf(v + EPSF);
        consts[CO_BND_S + t] = s;
        consts[CO_BND_B + t] = b[t] - m * s;
    }
}

// ---------------- K5: g_bn1 stats ----------------
// grid 1024 (b, 16-point chunk), block 256 (thread = channel c)
__global__ __launch_bounds__(256) void bn1_stats_kernel(
    const float* __restrict__ qproj, const float* __restrict__ kproj,
    const float* __restrict__ t3, const int* __restrict__ idx,
    const float* __restrict__ consts,
    const float* __restrict__ d2w, const float* __restrict__ d2b,
    float* __restrict__ stats)
{
    const int b   = blockIdx.x >> 8;
    const int pt0 = (blockIdx.x & 255) * 16;
    const int t = threadIdx.x;

    __shared__ float a3[768];
    __shared__ int idxs[256];

    const float bs[3]  = {consts[CO_BND_S+0], consts[CO_BND_S+1], consts[CO_BND_S+2]};
    const float bsh[3] = {consts[CO_BND_B+0], consts[CO_BND_B+1], consts[CO_BND_B+2]};
    const float* t3b = t3 + (size_t)(b * NN + pt0) * KK * 3;
    #pragma unroll
    for (int q = 0; q < 3; ++q) {
        const int f = t + q * 256;
        const int j = f % 3;
        a3[f] = fmaxf(fmaf(t3b[f], bs[j], bsh[j]), 0.f);
    }
    idxs[t] = idx[(size_t)(b * NN + pt0) * KK + t];
    __syncthreads();

    const int c = t;
    const float d20 = d2w[c], d21 = d2w[CC + c], d22 = d2w[2*CC + c], d2bc = d2b[c];
    float s = 0.f, sq = 0.f;
    for (int p = 0; p < 16; ++p) {
        const float qv = qproj[(size_t)(b * NN + pt0 + p) * CC + c];
        #pragma unroll
        for (int k = 0; k < 16; ++k) {
            const int mi = idxs[p*16 + k];
            const float kv = kproj[((size_t)b * NN + mi) * CC + c];
            const int f = (p*16 + k) * 3;
            const float pe = fmaf(a3[f], d20, fmaf(a3[f+1], d21, fmaf(a3[f+2], d22, d2bc)));
            const float h = qv - kv + pe;
            s += h; sq = fmaf(h, h, sq);
        }
    }
    atomicAdd(&stats[ST_G1_SUM + c], s);
    atomicAdd(&stats[ST_G1_SQ + c], sq);
}

// ---------------- finalize g_bn (shared by bn1 / bn2) ----------------
__global__ void finalize_g(const float* __restrict__ ssum, const float* __restrict__ ssq,
                           const float* __restrict__ g, const float* __restrict__ b,
                           float* __restrict__ os, float* __restrict__ ob)
{
    const int c = threadIdx.x;
    const float m = ssum[c] * MINVF;
    const float v = ssq[c] * MINVF - m * m;
    const float s = g[c] / sqrtf(v + EPSF);
    os[c] = s;
    ob[c] = b[c] - m * s;
}

// ---------------- K7: stage3 — h2 = relu(bn1(h)) @ g1_w + g1_b; bn2 stats ----------------
template<bool STORE>
__global__ __launch_bounds__(256) void stage3_kernel(
    const float* __restrict__ qproj, const float* __restrict__ kproj,
    const float* __restrict__ t3, const int* __restrict__ idx,
    const float* __restrict__ consts, float* __restrict__ stats,
    const float* __restrict__ d2w, const float* __restrict__ d2b,
    const float* __restrict__ g1w, const float* __restrict__ g1b,
    __hip_bfloat16* __restrict__ h2)
{
    const size_t pt = blockIdx.x;            // b*N + n
    const int b = (int)(pt >> 12);
    const int t = threadIdx.x;

    __shared__ float a3[48];
    __shared__ int idxs[16];
    __shared__ __align__(16) float hr[16][256];

    if (t < 48) {
        const int j = t % 3;
        a3[t] = fmaxf(fmaf(t3[pt*48 + t], consts[CO_BND_S + j], consts[CO_BND_B + j]), 0.f);
    }
    if (t < 16) idxs[t] = idx[pt*16 + t];
    __syncthreads();

    {   // phase 1: h -> bn1 -> relu into LDS
        const int c = t;
        const float d20 = d2w[c], d21 = d2w[CC + c], d22 = d2w[2*CC + c], d2bc = d2b[c];
        const float g1s = consts[CO_G1_S + c], g1sh = consts[CO_G1_B + c];
        const float qv = qproj[pt * CC + c];
        #pragma unroll
        for (int k = 0; k < 16; ++k) {
            const int mi = idxs[k];
            const float kv = kproj[((size_t)b * NN + mi) * CC + c];
            const float pe = fmaf(a3[k*3], d20, fmaf(a3[k*3+1], d21, fmaf(a3[k*3+2], d22, d2bc)));
            const float h = qv - kv + pe;
            hr[k][c] = fmaxf(fmaf(h, g1s, g1sh), 0.f);
        }
    }
    __syncthreads();

    // phase 2: GEMM1 (16x256 @ 256x256), thread = output channel a
    float acc[16];
    const float gb = g1b[t];
    #pragma unroll
    for (int k = 0; k < 16; ++k) acc[k] = gb;
    #pragma unroll 4
    for (int c4 = 0; c4 < 64; ++c4) {
        const float* wp = g1w + (size_t)(c4*4) * AA + t;
        const float w0 = wp[0], w1 = wp[AA], w2 = wp[2*AA], w3 = wp[3*AA];
        #pragma unroll
        for (int k = 0; k < 16; ++k) {
            const float4 hv = *(const float4*)&hr[k][c4*4];
            acc[k] = fmaf(hv.x, w0, fmaf(hv.y, w1, fmaf(hv.z, w2, fmaf(hv.w, w3, acc[k]))));
        }
    }

    float s = 0.f, sq = 0.f;
    #pragma unroll
    for (int k = 0; k < 16; ++k) { s += acc[k]; sq = fmaf(acc[k], acc[k], sq); }
    atomicAdd(&stats[ST_G2_SUM + t], s);
    atomicAdd(&stats[ST_G2_SQ + t], sq);

    if (STORE) {
        #pragma unroll
        for (int k = 0; k < 16; ++k)
            h2[(pt*16 + k) * AA + t] = __float2bfloat16(acc[k]);
    }
}

// ---------------- K9: stage4 — GEMM2, softmax, combine ----------------
template<bool LOAD>
__global__ __launch_bounds__(256) void stage4_kernel(
    const float* __restrict__ qproj, const float* __restrict__ kproj,
    const float* __restrict__ vproj,
    const float* __restrict__ t3, const int* __restrict__ idx,
    const float* __restrict__ consts,
    const float* __restrict__ d2w, const float* __restrict__ d2b,
    const float* __restrict__ g1w, const float* __restrict__ g1b,
    const float* __restrict__ g2w, const float* __restrict__ g2b,
    const __hip_bfloat16* __restrict__ h2, float* __restrict__ out)
{
    const size_t pt = blockIdx.x;
    const int b = (int)(pt >> 12);
    const int t = threadIdx.x;

    __shared__ float a3[48];
    __shared__ int idxs[16];
    __shared__ __align__(16) float r2[16][256];

    if (t < 48) {
        const int j = t % 3;
        a3[t] = fmaxf(fmaf(t3[pt*48 + t], consts[CO_BND_S + j], consts[CO_BND_B + j]), 0.f);
    }
    if (t < 16) idxs[t] = idx[pt*16 + t];
    __syncthreads();

    const float g2s = consts[CO_G2_S + t], g2sh = consts[CO_G2_B + t];

    if constexpr (LOAD) {
        #pragma unroll
        for (int k = 0; k < 16; ++k) {
            const float v = __bfloat162float(h2[(pt*16 + k) * AA + t]);
            r2[k][t] = fmaxf(fmaf(v, g2s, g2sh), 0.f);
        }
        __syncthreads();
    } else {
        __shared__ __align__(16) float hr[16][256];
        {
            const int c = t;
            const float d20 = d2w[c], d21 = d2w[CC + c], d22 = d2w[2*CC + c], d2bc = d2b[c];
            const float g1s = consts[CO_G1_S + c], g1sh = consts[CO_G1_B + c];
            const float qv = qproj[pt * CC + c];
            #pragma unroll
            for (int k = 0; k < 16; ++k) {
                const int mi = idxs[k];
                const float kv = kproj[((size_t)b * NN + mi) * CC + c];
                const float pe = fmaf(a3[k*3], d20, fmaf(a3[k*3+1], d21, fmaf(a3[k*3+2], d22, d2bc)));
                const float h = qv - kv + pe;
                hr[k][c] = fmaxf(fmaf(h, g1s, g1sh), 0.f);
            }
        }
        __syncthreads();
        float acc[16];
        const float gb = g1b[t];
        #pragma unroll
        for (int k = 0; k < 16; ++k) acc[k] = gb;
        #pragma unroll 4
        for (int c4 = 0; c4 < 64; ++c4) {
            const float* wp = g1w + (size_t)(c4*4) * AA + t;
            const float w0 = wp[0], w1 = wp[AA], w2 = wp[2*AA], w3 = wp[3*AA];
            #pragma unroll
            for (int k = 0; k < 16; ++k) {
                const float4 hv = *(const float4*)&hr[k][c4*4];
                acc[k] = fmaf(hv.x, w0, fmaf(hv.y, w1, fmaf(hv.z, w2, fmaf(hv.w, w3, acc[k]))));
            }
        }
        __syncthreads();   // hr no longer needed
        #pragma unroll
        for (int k = 0; k < 16; ++k) r2[k][t] = fmaxf(fmaf(acc[k], g2s, g2sh), 0.f);
        __syncthreads();
    }

    // GEMM2: logits[k][a], thread = a
    float lg[16];
    const float gb2 = g2b[t];
    #pragma unroll
    for (int k = 0; k < 16; ++k) lg[k] = gb2;
    #pragma unroll 4
    for (int c4 = 0; c4 < 64; ++c4) {
        const float* wp = g2w + (size_t)(c4*4) * AA + t;
        const float w0 = wp[0], w1 = wp[AA], w2 = wp[2*AA], w3 = wp[3*AA];
        #pragma unroll
        for (int k = 0; k < 16; ++k) {
            const float4 hv = *(const float4*)&r2[k][c4*4];
            lg[k] = fmaf(hv.x, w0, fmaf(hv.y, w1, fmaf(hv.z, w2, fmaf(hv.w, w3, lg[k]))));
        }
    }

    // softmax over k (all in registers)
    float mx = lg[0];
    #pragma unroll
    for (int k = 1; k < 16; ++k) mx = fmaxf(mx, lg[k]);
    float sum = 0.f;
    #pragma unroll
    for (int k = 0; k < 16; ++k) { lg[k] = expf(lg[k] - mx); sum += lg[k]; }
    const float inv = 1.0f / sum;

    // combine: out = sum_k (v + pos_enc) * attn
    const float d20 = d2w[t], d21 = d2w[CC + t], d22 = d2w[2*CC + t], d2bc = d2b[t];
    float o = 0.f;
    #pragma unroll
    for (int k = 0; k < 16; ++k) {
        const int mi = idxs[k];
        const float vv = vproj[((size_t)b * NN + mi) * CC + t];
        const float pe = fmaf(a3[k*3], d20, fmaf(a3[k*3+1], d21, fmaf(a3[k*3+2], d22, d2bc)));
        o = fmaf(vv + pe, lg[k] * inv, o);
    }
    out[pt * CC + t] = o;
}

// ---------------- host ----------------
extern "C" void kernel_launch(void* const* d_in, const int* in_sizes, int n_in,
                              void* d_out, int out_size, void* d_ws, size_t ws_size,
                              hipStream_t stream)
{
    const float* xyz   = (const float*)d_in[0];
    const float* feat  = (const float*)d_in[1];
    const float* wq    = (const float*)d_in[2];
    const float* bq    = (const float*)d_in[3];
    const float* wk    = (const float*)d_in[4];
    const float* bk    = (const float*)d_in[5];
    const float* wv    = (const float*)d_in[6];
    const float* bv    = (const float*)d_in[7];
    const float* d1w   = (const float*)d_in[8];
    const float* d1b   = (const float*)d_in[9];
    const float* bndg  = (const float*)d_in[10];
    const float* bndb  = (const float*)d_in[11];
    const float* d2w   = (const float*)d_in[12];
    const float* d2b   = (const float*)d_in[13];
    const float* g1g   = (const float*)d_in[14];
    const float* g1bb  = (const float*)d_in[15];
    const float* g1w   = (const float*)d_in[16];
    const float* g1b   = (const float*)d_in[17];
    const float* g2g   = (const float*)d_in[18];
    const float* g2bb  = (const float*)d_in[19];
    const float* g2w   = (const float*)d_in[20];
    const float* g2b   = (const float*)d_in[21];
    float* out = (float*)d_out;

    // workspace layout
    float* qproj = (float*)d_ws;
    float* kproj = qproj + (size_t)NPTS * CC;
    float* vproj = kproj + (size_t)NPTS * CC;
    float* t3    = vproj + (size_t)NPTS * CC;
    float* stats = t3 + (size_t)BNKTOT * 3;
    float* consts = stats + 2048;
    int*   idxb  = (int*)(consts + 2048);
    __hip_bfloat16* h2 = (__hip_bfloat16*)(idxb + BNKTOT);
    const size_t need_store = (size_t)((char*)h2 - (char*)d_ws) + (size_t)BNKTOT * AA * 2;
    const bool store = ws_size >= need_store;

    hipMemsetAsync(stats, 0, 2048 * sizeof(float), stream);

    dim3 gq(NPTS / 64, 3);
    qkv_kernel<<<gq, 256, 0, stream>>>(feat, wq, bq, wk, bk, wv, bv, qproj, kproj, vproj);

    knn_kernel<<<512, 256, 0, stream>>>(xyz, idxb);

    fc_delta_kernel<<<BNKTOT / 256, 256, 0, stream>>>(xyz, idxb, d1w, d1b, t3, stats);

    finalize_bnd<<<1, 64, 0, stream>>>(stats, bndg, bndb, consts);

    bn1_stats_kernel<<<1024, 256, 0, stream>>>(qproj, kproj, t3, idxb, consts, d2w, d2b, stats);

    finalize_g<<<1, 256, 0, stream>>>(stats + ST_G1_SUM, stats + ST_G1_SQ, g1g, g1bb,
                                      consts + CO_G1_S, consts + CO_G1_B);

    if (store)
        stage3_kernel<true><<<NPTS, 256, 0, stream>>>(qproj, kproj, t3, idxb, consts, stats,
                                                      d2w, d2b, g1w, g1b, h2);
    else
        stage3_kernel<false><<<NPTS, 256, 0, stream>>>(qproj, kproj, t3, idxb, consts, stats,
                                                       d2w, d2b, g1w, g1b, h2);

    finalize_g<<<1, 256, 0, stream>>>(stats + ST_G2_SUM, stats + ST_G2_SQ, g2g, g2bb,
                                      consts + CO_G2_S, consts + CO_G2_B);

    if (store)
        stage4_kernel<true><<<NPTS, 256, 0, stream>>>(qproj, kproj, vproj, t3, idxb, consts,
                                                      d2w, d2b, g1w, g1b, g2w, g2b, h2, out);
    else
        stage4_kernel<false><<<NPTS, 256, 0, stream>>>(qproj, kproj, vproj, t3, idxb, consts,
                                                       d2w, d2b, g1w, g1b, g2w, g2b, h2, out);
}